// Round 2
// baseline (1475.982 us; speedup 1.0000x reference)
//
#include <hip/hip_runtime.h>
#include <math.h>

// Max-plus DP: out[b,t,k] = x[b,t,k] + max(out[b,t-1,k], out[b,t-1,k-1])
// 32 batches x 4 column groups = 128 blocks, 1 wave each, 4 cols/lane (float4).
// vs previous (8 groups x 2 cols/lane): per-row fixed latency (shfl, drains,
// handoffs) is amortized over 2x the columns, the boundary broadcast uses
// readlane (VALU) instead of a DS shfl, and the remaining shfl_up is issued
// right after n3 (first op of the row) and consumed only late in the NEXT
// row, so its DS latency hides under a full row of work.
// Cross-block protocol (relaxed agent atomics + vmcnt(0) drain + lag-2 flags)
// is unchanged from the verified kernel.

#define BB 32
#define TT 2048
#define KK 1024
#define GG 4
#define WW (KK / GG)      // 256 cols per group
#define RR 32             // rows per tile (flag granularity, prefetch depth)
#define NT (TT / RR)      // 64 tiles

__global__ __launch_bounds__(64, 1)
void harddtw_pipe4(const float* __restrict__ x, float* __restrict__ out,
                   int* __restrict__ flags)
{
    const int bid  = blockIdx.x;
    const int g    = bid >> 5;   // column group 0..3
    const int b    = bid & 31;   // batch
    const int lane = threadIdx.x;
    const bool lz  = (lane == 0);

    const int k0 = g * WW;
    const int kc = k0 + (lane << 2);           // 4 cols per lane
    const size_t base = (size_t)b * TT * KK;

    const float* xl = x + base + kc;           // this lane's x column quad
    float*       ol = out + base + kc;         // out cursor (row 0)
    const float* bb = out + base + (k0 - 1);   // boundary column (g>0 only)

    int* myflag = flags + bid;
    int* upflag = flags + bid - 32;            // same batch, group g-1

    // --- register prefetch ring: rows t..t+31 in flight (float4 = 128 VGPR) ---
    float4 buf[RR];
#pragma unroll
    for (int j = 0; j < RR; ++j)
        buf[j] = *(const float4*)(xl + (size_t)j * KK);
    const float* xpre = xl + (size_t)RR * KK;  // next row to prefetch

    float pv0 = 0.0f, pv1 = 0.0f, pv2 = 0.0f, pv3 = 0.0f; // prev row (0 => row0 = x)
    float sh_prev = 0.0f;                      // left-neighbor pv3 from "row -1"
    float bcur = -INFINITY, bnxt = -INFINITY;  // boundary vals, lane j = row j-1 of tile

    if (g > 0) {
        // tile 0 boundary: rows -1..30 of column k0-1
        while (__hip_atomic_load(upflag, __ATOMIC_RELAXED,
                                 __HIP_MEMORY_SCOPE_AGENT) < 1)
            __builtin_amdgcn_s_sleep(1);
        __asm__ volatile("" ::: "memory");
        if (lane == 0) {
            bcur = 0.0f;                       // row -1: x + max(0,0) = x
        } else if (lane < RR) {
            bcur = __hip_atomic_load(bb + (size_t)(lane - 1) * KK,
                                     __ATOMIC_RELAXED, __HIP_MEMORY_SCOPE_AGENT);
        }
    }

#pragma unroll 1
    for (int r = 0; r < NT; ++r) {
        // Lag-2: require producer 2 tiles ahead, then issue next tile's
        // boundary loads now so their ~900cy latency hides behind this tile.
        if (g > 0 && r < NT - 1) {
            while (__hip_atomic_load(upflag, __ATOMIC_RELAXED,
                                     __HIP_MEMORY_SCOPE_AGENT) < r + 2)
                __builtin_amdgcn_s_sleep(1);
            __asm__ volatile("" ::: "memory");
            if (lane < RR)
                bnxt = __hip_atomic_load(
                    bb + (size_t)((r + 1) * RR + lane - 1) * KK,
                    __ATOMIC_RELAXED, __HIP_MEMORY_SCOPE_AGENT);
        }

        const bool pref = (r < NT - 1);
        const bool pub  = (g < GG - 1);

#pragma unroll
        for (int j = 0; j < RR; ++j) {
            float4 xv = buf[j];
            // Rightmost column first: depends only on in-lane registers.
            float n3 = xv.w + fmaxf(pv3, pv2);
            // Issue the cross-lane shfl NOW; its result is consumed only at
            // the end of the NEXT row, so DS latency hides under ~1 row.
            float sh_new = __shfl_up(n3, 1);
            float n2 = xv.z + fmaxf(pv2, pv1);
            float n1 = xv.y + fmaxf(pv1, pv0);
            // Boundary value for this row: uniform readlane (VALU, no DS).
            float bv = __int_as_float(
                __builtin_amdgcn_readlane(__float_as_int(bcur), j));
            float left = lz ? bv : sh_prev;    // sh_prev = prev row's shfl
            float n0 = xv.x + fmaxf(pv0, left);

            float4 o; o.x = n0; o.y = n1; o.z = n2; o.w = n3;
            *(float4*)ol = o;
            if (pub && lane == 63) {
                // Consumer only reads our last column: push n3 to the
                // coherence point (same value as the plain store — benign).
                __hip_atomic_store(ol + 3, n3, __ATOMIC_RELAXED,
                                   __HIP_MEMORY_SCOPE_AGENT);
            }
            ol += KK;
            if (pref) {                        // prefetch row t+RR into slot j
                buf[j] = *(const float4*)xpre;
                xpre += KK;
            }
            pv0 = n0; pv1 = n1; pv2 = n2; pv3 = n3;
            sh_prev = sh_new;
            // Pin the software pipeline: nothing crosses row boundaries.
            __builtin_amdgcn_sched_barrier(0);
        }

        bcur = bnxt;

        if (pub) {
            // Drain our stores to the coherence point, then publish.
            __asm__ volatile("s_waitcnt vmcnt(0)" ::: "memory");
            if (lane == 0)
                __hip_atomic_store(myflag, r + 1, __ATOMIC_RELAXED,
                                   __HIP_MEMORY_SCOPE_AGENT);
        }
    }
}

extern "C" void kernel_launch(void* const* d_in, const int* in_sizes, int n_in,
                              void* d_out, int out_size, void* d_ws, size_t ws_size,
                              hipStream_t stream) {
    (void)in_sizes; (void)n_in; (void)out_size; (void)ws_size;
    const float* x = (const float*)d_in[0];
    float* out = (float*)d_out;
    int* flags = (int*)d_ws;

    // ws is re-poisoned to 0xAA before every timed launch; flags must be 0.
    hipMemsetAsync(flags, 0, BB * GG * sizeof(int), stream);

    harddtw_pipe4<<<dim3(BB * GG), dim3(64), 0, stream>>>(x, out, flags);
}

// Round 3
// 891.118 us; speedup vs baseline: 1.6563x; 1.6563x over previous
//
#include <hip/hip_runtime.h>
#include <math.h>

// Max-plus DP: out[b,t,k] = x[b,t,k] + max(out[b,t-1,k], out[b,t-1,k-1])
// 32 batches x 8 column groups = 256 blocks, 1 wave each, 2 cols/lane.
//
// Key fix vs the 573us/dispatch baseline: the baseline stored each row from
// the loop-carried pv registers, which are rewritten on the NEXT row. CDNA
// requires s_waitcnt before overwriting an in-flight store's source VGPRs,
// so every row stalled ~500cy on the previous row's store retire
// (measured: ~550cy/row, VALUBusy 0.85%, ~1.7 B/cy/CU).
// Now: row i's output is staged into ring[i&31] (the slot whose x it just
// consumed) and stored from there; that slot is not rewritten until the
// prefetch at row i+16, giving the store 16 rows (~1000cy) of slack. A
// zero-cost asm dummy-use keeps the staged value live so the allocator
// cannot recycle the store-source registers early.
// Prefetch depth is 16 rows (covers ~900cy HBM latency).
// Cross-block protocol (relaxed agent atomics + vmcnt(0) drain + lag-2
// flags) is unchanged from the verified kernel.

#define BB 32
#define TT 2048
#define KK 1024
#define GG 8
#define WW (KK / GG)      // 128 cols per group
#define RR 32             // rows per tile (flag granularity, ring size)
#define PD 16             // prefetch depth / store-source slack, rows
#define NT (TT / RR)      // 64 tiles

__global__ __launch_bounds__(64, 1)
void harddtw_ring(const float* __restrict__ x, float* __restrict__ out,
                  int* __restrict__ flags)
{
    const int bid  = blockIdx.x;
    const int g    = bid >> 5;   // column group 0..7
    const int b    = bid & 31;   // batch
    const int lane = threadIdx.x;
    const bool lz  = (lane == 0);

    const int k0 = g * WW;
    const int kc = k0 + (lane << 1);
    const size_t base = (size_t)b * TT * KK;

    const float* xl = x + base + kc;           // this lane's x column pair
    float*       ol = out + base + kc;         // out cursor (row 0)
    const float* bb = out + base + (k0 - 1);   // boundary column (g>0 only)

    int* myflag = flags + bid;
    int* upflag = flags + bid - 32;            // same batch, group g-1

    // --- 32-slot ring: slot s holds x for row (i: i&31==s) until that row
    // consumes it, then holds row i's OUTPUT until the prefetch at i+PD. ---
    float2 ring[RR];
#pragma unroll
    for (int j = 0; j < PD; ++j)
        ring[j] = *(const float2*)(xl + (size_t)j * KK);
    const float* xpre = xl + (size_t)PD * KK;  // next x row to prefetch

    float pv0 = 0.0f, pv1 = 0.0f;              // prev-row values (0 => row0 = x)
    float sh_prev = 0.0f;                      // left-neighbor pv1 from "row -1"
    float bcur = -INFINITY, bnxt = -INFINITY;  // boundary vals, lane j = row j-1 of tile

    if (g > 0) {
        // tile 0 boundary: rows -1..30 of column k0-1
        while (__hip_atomic_load(upflag, __ATOMIC_RELAXED,
                                 __HIP_MEMORY_SCOPE_AGENT) < 1)
            __builtin_amdgcn_s_sleep(1);
        __asm__ volatile("" ::: "memory");
        if (lane == 0) {
            bcur = 0.0f;                       // row -1 virtual: max(0,0)
        } else if (lane < RR) {
            bcur = __hip_atomic_load(bb + (size_t)(lane - 1) * KK,
                                     __ATOMIC_RELAXED, __HIP_MEMORY_SCOPE_AGENT);
        }
    }

#pragma unroll 1
    for (int r = 0; r < NT; ++r) {
        // Lag-2: require producer 2 tiles ahead, then issue next tile's
        // boundary loads now so their latency hides behind this tile.
        if (g > 0 && r < NT - 1) {
            while (__hip_atomic_load(upflag, __ATOMIC_RELAXED,
                                     __HIP_MEMORY_SCOPE_AGENT) < r + 2)
                __builtin_amdgcn_s_sleep(1);
            __asm__ volatile("" ::: "memory");
            if (lane < RR)
                bnxt = __hip_atomic_load(
                    bb + (size_t)((r + 1) * RR + lane - 1) * KK,
                    __ATOMIC_RELAXED, __HIP_MEMORY_SCOPE_AGENT);
        }

        const bool pub  = (g < GG - 1);
        const bool last = (r == NT - 1);

#pragma unroll
        for (int j = 0; j < RR; ++j) {
            float2 xv = ring[j];
            // Consume last row's shfl FIRST (it has had a full row to land),
            // then issue this row's shfl late so lgkmcnt(0) here is free.
            float bv = __int_as_float(
                __builtin_amdgcn_readlane(__float_as_int(bcur), j));
            float left = lz ? bv : sh_prev;
            float n0 = xv.x + fmaxf(pv0, left);
            float n1 = xv.y + fmaxf(pv1, pv0);
            float sh_new = __shfl_up(n1, 1);   // consumed next row

            float2 o; o.x = n0; o.y = n1;
            ring[j] = o;                       // stage output in ring slot
            if (pub && lane == 63) {
                // Consumer reads our boundary pair via agent atomics only.
                union { float2 f; unsigned long long u; } cv; cv.f = o;
                __hip_atomic_store((unsigned long long*)ol, cv.u,
                                   __ATOMIC_RELAXED, __HIP_MEMORY_SCOPE_AGENT);
            } else {
                *(float2*)ol = o;
            }
            ol += KK;

            // Pin the slot we are about to overwrite live until HERE: its
            // staged output (stored PD rows ago) must keep its registers
            // until the store has surely consumed them.
            asm volatile("" :: "v"(ring[(j + PD) & (RR - 1)].x),
                              "v"(ring[(j + PD) & (RR - 1)].y));
            if (!last || j < RR - PD) {        // prefetch row i+PD
                ring[(j + PD) & (RR - 1)] = *(const float2*)xpre;
                xpre += KK;
            }

            pv0 = n0; pv1 = n1; sh_prev = sh_new;
            __builtin_amdgcn_sched_barrier(0);
        }

        bcur = bnxt;

        if (pub) {
            // Drain our stores to the coherence point, then publish.
            __asm__ volatile("s_waitcnt vmcnt(0)" ::: "memory");
            if (lane == 0)
                __hip_atomic_store(myflag, r + 1, __ATOMIC_RELAXED,
                                   __HIP_MEMORY_SCOPE_AGENT);
        }
    }
}

extern "C" void kernel_launch(void* const* d_in, const int* in_sizes, int n_in,
                              void* d_out, int out_size, void* d_ws, size_t ws_size,
                              hipStream_t stream) {
    (void)in_sizes; (void)n_in; (void)out_size; (void)ws_size;
    const float* x = (const float*)d_in[0];
    float* out = (float*)d_out;
    int* flags = (int*)d_ws;

    // ws is re-poisoned to 0xAA before every timed launch; flags must be 0.
    hipMemsetAsync(flags, 0, BB * GG * sizeof(int), stream);

    harddtw_ring<<<dim3(BB * GG), dim3(64), 0, stream>>>(x, out, flags);
}